// Round 13
// baseline (100.872 us; speedup 1.0000x reference)
//
#include <hip/hip_runtime.h>
#include <math.h>

typedef __bf16 bf16x8 __attribute__((ext_vector_type(8)));
typedef float f32x4 __attribute__((ext_vector_type(4)));
typedef unsigned short u16;
typedef unsigned short u16x8 __attribute__((ext_vector_type(8)));
typedef unsigned int u32;

constexpr int BATCH = 2048;
constexpr int HID   = 512;
constexpr int NACT  = 8;

__device__ __forceinline__ float gelu_f(float x) {
    return 0.5f * x * (1.0f + erff(x * 0.70710678118654752f));
}
__device__ __forceinline__ u16 f2bf(float f) {
    u32 u = __float_as_uint(f);
    return (u16)((u + 0x7FFFu + ((u >> 16) & 1u)) >> 16);
}
__device__ __forceinline__ float bf2f(u16 h) {
    return __uint_as_float(((u32)h) << 16);
}

// Fragment-chunk layout (round-10 proven): plane[(r>>4)*16 + (k>>5)][512],
// idx = (((k&31)>>3)*16 + (r&15))*8 + (k&7). One 16-row x 32-k tile = one
// contiguous 1KB block in exact MFMA lane order (lane l -> u16[8] at l*8).
__device__ __forceinline__ size_t fragoff(int r, int k) {
    return (size_t)(((r >> 4) * 16 + (k >> 5)) * 512
                    + (((k & 31) >> 3) * 16 + (r & 15)) * 8 + (k & 7));
}

// ---------------------------------------------------------------------------
// K_prep: z<4 -> transpose + hi/lo-split weight layer z into wt (frag layout)
//         z==4 (x<4,y==0) -> partials[x] = temb-slice @ W_in slice (no
//         cross-block reduction: summed by consumers; deterministic).
// ---------------------------------------------------------------------------
__global__ __launch_bounds__(256) void k_prep(
        const float* __restrict__ W1, const float* __restrict__ W2,
        const float* __restrict__ W3, const float* __restrict__ W4,
        const float* __restrict__ W_in,
        u16* __restrict__ wt, float* __restrict__ partials) {
    int z = blockIdx.z;
    if (z == 4) {
        if (blockIdx.x >= 4 || blockIdx.y != 0) return;
        __shared__ float temb[128];
        int x = blockIdx.x, t = threadIdx.x;
        if (t < 128) {
            int k = x * 128 + t;
            int p = k >> 1;
            float div = expf((float)(2 * p) * (-9.210340371976184f / 512.0f));
            temb[t] = (k & 1) ? cosf(49.0f * div) : sinf(49.0f * div);
        }
        __syncthreads();
#pragma unroll
        for (int half = 0; half < 2; ++half) {
            int col = half * 256 + t;
            float acc = 0.f;
            for (int kk = 0; kk < 128; ++kk)
                acc += temb[kk] * W_in[(size_t)(14 + x * 128 + kk) * HID + col];
            partials[x * HID + col] = acc;
        }
        return;
    }
    __shared__ float tile[32][33];
    const float* Ws[4] = {W1, W2, W3, W4};
    const float* W = Ws[z];
    u16* wh = wt + (size_t)z * 524288;
    u16* wl = wh + 262144;
    int kt = blockIdx.x * 32, nt = blockIdx.y * 32, t = threadIdx.x;
    int c = t & 31, r = t >> 5;
#pragma unroll
    for (int p = 0; p < 4; ++p)
        tile[r + p * 8][c] = W[(size_t)(kt + r + p * 8) * HID + nt + c];
    __syncthreads();
#pragma unroll
    for (int p = 0; p < 4; ++p) {
        int nl = r + p * 8, kl = c;
        float v = tile[kl][nl];
        u16 h = f2bf(v);
        u16 l2 = f2bf(v - bf2f(h));
        size_t o = fragoff(nt + nl, kt + kl);
        wh[o] = h;
        wl[o] = l2;
    }
}

// ---------------------------------------------------------------------------
// K_mlp: ENTIRE network, one kernel, zero grid syncs, zero in-loop barriers.
// 256 blocks x 512 thr (8 waves, 1 block/CU). Block owns 8 batch elements x
// both steps = 16 rows; activations LDS-resident (A[2][16][512], 32 KB),
// read-only during each layer's K-loop -> only 2 __syncthreads per layer.
// Wave w computes the block's 16 rows x cols [64w, 64w+64): per k-chunk
// 2 ds_read_b128 (A hi/lo, shared) + 8 contiguous-1KB global loads (B frag
// -> REGISTERS, 3-buffer 2-deep prefetch, compiler-scheduled waits) + 12
// MFMAs (4 col-groups x 3-pass split-bf16). Weights are L2-resident (4 MB
// per XCD). Layer epilogue: bias+gelu+hi/lo-split written back to A (each
// wave writes only its own col-chunks 2w,2w+1 -> disjoint).
// Tail: output layer + DDIM + tanh + FK + select fused (rows are step-paired
// by construction: batch b0+w lives at local rows w and 8+w).
// ---------------------------------------------------------------------------
__device__ void mat4mul(float C[4][4], const float A[4][4], const float Bm[4][4]) {
#pragma unroll
    for (int i = 0; i < 4; ++i)
#pragma unroll
        for (int j = 0; j < 4; ++j) {
            float s = A[i][0] * Bm[0][j];
            s += A[i][1] * Bm[1][j];
            s += A[i][2] * Bm[2][j];
            s += A[i][3] * Bm[3][j];
            C[i][j] = s;
        }
}

__global__ __launch_bounds__(512) void k_mlp(
        const float* __restrict__ x_pre, const float* __restrict__ noise,
        const float* __restrict__ W_in, const float* __restrict__ b_in,
        const float* __restrict__ partials, const u16* __restrict__ wt,
        const float* __restrict__ b1, const float* __restrict__ b2,
        const float* __restrict__ b3, const float* __restrict__ b4,
        const float* __restrict__ W_out, const float* __restrict__ b_out,
        float* __restrict__ out, float c1, float c2, float c3) {
    __shared__ __align__(16) u16 A[2][16][512];   // [plane][kchunk][frag] 32 KB
    int tid = threadIdx.x, lane = tid & 63, w = tid >> 6;
    int l15 = lane & 15;
    int b0 = blockIdx.x * 8;

    // ---- Phase 0: input layer for this block's 16 rows (computed ONCE) ----
#pragma unroll
    for (int rep = 0; rep < 2; ++rep) {
        int id = tid + rep * 512;
        int r = id & 15, oct = id >> 4;       // local row, col-octet
        int st = r >> 3, be = b0 + (r & 7);
        float xv[6], nz[8];
#pragma unroll
        for (int j = 0; j < 6; ++j) xv[j] = x_pre[be * 6 + j];
#pragma unroll
        for (int j = 0; j < 8; ++j) nz[j] = noise[(st * BATCH + be) * NACT + j];
        int nc = oct * 8;
        float acc[8];
#pragma unroll
        for (int q = 0; q < 2; ++q) {
            float4 bv = *(const float4*)&b_in[nc + q * 4];
            float4 p0 = *(const float4*)&partials[nc + q * 4];
            float4 p1 = *(const float4*)&partials[512 + nc + q * 4];
            float4 p2 = *(const float4*)&partials[1024 + nc + q * 4];
            float4 p3 = *(const float4*)&partials[1536 + nc + q * 4];
            acc[q * 4 + 0] = bv.x + p0.x + p1.x + p2.x + p3.x;
            acc[q * 4 + 1] = bv.y + p0.y + p1.y + p2.y + p3.y;
            acc[q * 4 + 2] = bv.z + p0.z + p1.z + p2.z + p3.z;
            acc[q * 4 + 3] = bv.w + p0.w + p1.w + p2.w + p3.w;
        }
#pragma unroll
        for (int j = 0; j < 14; ++j) {
            float xj = (j < 6) ? xv[j] : nz[j - 6];
            float4 wa = *(const float4*)&W_in[j * HID + nc];
            float4 wb = *(const float4*)&W_in[j * HID + nc + 4];
            acc[0] += xj * wa.x; acc[1] += xj * wa.y;
            acc[2] += xj * wa.z; acc[3] += xj * wa.w;
            acc[4] += xj * wb.x; acc[5] += xj * wb.y;
            acc[6] += xj * wb.z; acc[7] += xj * wb.w;
        }
        u16x8 hv, lv;
#pragma unroll
        for (int j2 = 0; j2 < 8; ++j2) {
            float g = gelu_f(acc[j2]);
            u16 hi = f2bf(g);
            hv[j2] = hi;
            lv[j2] = f2bf(g - bf2f(hi));
        }
        int ch = nc >> 5;
        int idx = (((nc & 31) >> 3) * 16 + r) * 8;
        *(u16x8*)&A[0][ch][idx] = hv;
        *(u16x8*)&A[1][ch][idx] = lv;
    }
    __syncthreads();

    // ---- Phases 1..4: hidden layers, A LDS-resident, B reg-streamed ----
    const u16* wh_l[4] = {wt, wt + 524288, wt + 1048576, wt + 1572864};
    const float* bias_l[4] = {b1, b2, b3, b4};
    int g4 = 4 * w;   // wave's first col-group

#pragma unroll 1
    for (int l = 0; l < 4; ++l) {
        const u16* Wh  = wh_l[l];
        const u16* Wl2 = Wh + 262144;
        f32x4 zero = {0.f, 0.f, 0.f, 0.f};
        f32x4 acc[4] = {zero, zero, zero, zero};
        bf16x8 bh[3][4], bl[3][4];   // 3-slot register prefetch (2-deep)
#pragma unroll
        for (int g = 0; g < 4; ++g) {
            bh[0][g] = *(const bf16x8*)(Wh  + (size_t)((g4 + g) * 16 + 0) * 512 + lane * 8);
            bl[0][g] = *(const bf16x8*)(Wl2 + (size_t)((g4 + g) * 16 + 0) * 512 + lane * 8);
            bh[1][g] = *(const bf16x8*)(Wh  + (size_t)((g4 + g) * 16 + 1) * 512 + lane * 8);
            bl[1][g] = *(const bf16x8*)(Wl2 + (size_t)((g4 + g) * 16 + 1) * 512 + lane * 8);
        }
#pragma unroll
        for (int c = 0; c < 16; ++c) {
            const int cur = c % 3;
            if (c < 14) {
                const int nxt = (c + 2) % 3;
#pragma unroll
                for (int g = 0; g < 4; ++g) {
                    bh[nxt][g] = *(const bf16x8*)(Wh  + (size_t)((g4 + g) * 16 + c + 2) * 512 + lane * 8);
                    bl[nxt][g] = *(const bf16x8*)(Wl2 + (size_t)((g4 + g) * 16 + c + 2) * 512 + lane * 8);
                }
            }
            bf16x8 ah = *(const bf16x8*)&A[0][c][lane * 8];
            bf16x8 al = *(const bf16x8*)&A[1][c][lane * 8];
#pragma unroll
            for (int g = 0; g < 4; ++g) {
                acc[g] = __builtin_amdgcn_mfma_f32_16x16x32_bf16(ah, bh[cur][g], acc[g], 0, 0, 0);
                acc[g] = __builtin_amdgcn_mfma_f32_16x16x32_bf16(ah, bl[cur][g], acc[g], 0, 0, 0);
                acc[g] = __builtin_amdgcn_mfma_f32_16x16x32_bf16(al, bh[cur][g], acc[g], 0, 0, 0);
            }
        }
        __syncthreads();   // all waves done READING A for this layer
        const float* bias = bias_l[l];
#pragma unroll
        for (int g = 0; g < 4; ++g) {
            int col = w * 64 + g * 16 + l15;
            float bia = bias[col];
            int ch = col >> 5;
#pragma unroll
            for (int r2 = 0; r2 < 4; ++r2) {
                int row = (lane >> 4) * 4 + r2;
                float gv = gelu_f(acc[g][r2] + bia);
                u16 hi = f2bf(gv);
                int idx = (((col & 31) >> 3) * 16 + row) * 8 + (col & 7);
                A[0][ch][idx] = hi;
                A[1][ch][idx] = f2bf(gv - bf2f(hi));
            }
        }
        __syncthreads();   // A ready for next consumer
    }

    // ---- Phase 5: output layer + DDIM + tanh + FK + select -> d_out ----
    {
        int be = b0 + w;   // wave w: batch element be (local rows w and 8+w)
        float acc0[8] = {0, 0, 0, 0, 0, 0, 0, 0};
        float acc1[8] = {0, 0, 0, 0, 0, 0, 0, 0};
#pragma unroll
        for (int it = 0; it < 8; ++it) {
            int k = lane + it * 64;
            int ch = k >> 5;
            int base = ((k & 31) >> 3) * 16;
            int ko = k & 7;
            float ya = bf2f(A[0][ch][(base + w) * 8 + ko]) + bf2f(A[1][ch][(base + w) * 8 + ko]);
            float yb = bf2f(A[0][ch][(base + 8 + w) * 8 + ko]) + bf2f(A[1][ch][(base + 8 + w) * 8 + ko]);
            float4 w0 = ((const float4*)&W_out[k * NACT])[0];
            float4 w1 = ((const float4*)&W_out[k * NACT])[1];
            acc0[0] += ya * w0.x; acc0[1] += ya * w0.y; acc0[2] += ya * w0.z; acc0[3] += ya * w0.w;
            acc0[4] += ya * w1.x; acc0[5] += ya * w1.y; acc0[6] += ya * w1.z; acc0[7] += ya * w1.w;
            acc1[0] += yb * w0.x; acc1[1] += yb * w0.y; acc1[2] += yb * w0.z; acc1[3] += yb * w0.w;
            acc1[4] += yb * w1.x; acc1[5] += yb * w1.y; acc1[6] += yb * w1.z; acc1[7] += yb * w1.w;
        }
#pragma unroll
        for (int n = 0; n < 8; ++n) {
#pragma unroll
            for (int off = 32; off > 0; off >>= 1) {
                acc0[n] += __shfl_xor(acc0[n], off, 64);
                acc1[n] += __shfl_xor(acc1[n], off, 64);
            }
        }

        float jq[8] = {0, 0, 0, 0, 0, 0, 0, 0};
        float err = 0.f;
        if (lane < 2) {
            int s = lane;
            const float* accp = (s == 0) ? acc0 : acc1;
            const float HIf[8] = {
                (float)(35.0 * M_PI / 180.0), (float)(-60.0 * M_PI / 180.0), 3.94f,
                (float)(155.0 * M_PI / 180.0), (float)(-55.0 * M_PI / 180.0),
                (float)M_PI, (float)(5.0 * M_PI / 180.0), 3.71f};
            const float LOf[8] = {
                (float)(-35.0 * M_PI / 180.0), (float)(-155.0 * M_PI / 180.0), 2.59f,
                (float)(60.0 * M_PI / 180.0), (float)(-125.0 * M_PI / 180.0),
                (float)(-M_PI), (float)(-90.0 * M_PI / 180.0), 2.5f};
            const float* nzp = &noise[(s * BATCH + be) * NACT];
#pragma unroll
            for (int n = 0; n < 8; ++n) {
                float o = accp[n] + b_out[n];
                float z = c1 * nzp[n] + c2 * o + c3 * nzp[n];
                float jn = (tanhf(z * 0.1f) + 1.0f) * 0.5f;
                jq[n] = jn * (HIf[n] - LOf[n]) + LOf[n];
            }
            const float a_[8]  = {0.0f, 0.16f, 0.07f, 0.0f, 0.1334f, 0.0f, 0.15f, 0.3625f};
            const float ca_[8] = {1.f, 0.f, 0.f, 0.f, 0.f, 0.f, 0.f, 0.f};
            const float sa_[8] = {0.f, -1.f, -1.f, 1.f, -1.f, -1.f, 1.f, -1.f};
            float d_[8] = {0.0f, 0.0f, jq[2], 0.0f, -0.1316f, 1.0105f, 0.52f, jq[7]};
            float th[8] = {jq[0], jq[1], 0.0f, jq[3], jq[4], jq[5], jq[6], 0.0f};
            float T[4][4], M[4][4], Tn[4][4];
#pragma unroll
            for (int j = 0; j < 8; ++j) {
                float ct = cosf(th[j]);
                float st = sinf(th[j]);
                M[0][0] = ct;          M[0][1] = -st;         M[0][2] = 0.0f;    M[0][3] = a_[j];
                M[1][0] = st * ca_[j]; M[1][1] = ct * ca_[j]; M[1][2] = -sa_[j]; M[1][3] = -sa_[j] * d_[j];
                M[2][0] = st * sa_[j]; M[2][1] = ct * sa_[j]; M[2][2] = ca_[j];  M[2][3] = ca_[j] * d_[j];
                M[3][0] = 0.0f;        M[3][1] = 0.0f;        M[3][2] = 0.0f;    M[3][3] = 1.0f;
                if (j == 0) {
#pragma unroll
                    for (int i = 0; i < 4; ++i)
#pragma unroll
                        for (int cc = 0; cc < 4; ++cc) T[i][cc] = M[i][cc];
                } else {
                    mat4mul(Tn, T, M);
#pragma unroll
                    for (int i = 0; i < 4; ++i)
#pragma unroll
                        for (int cc = 0; cc < 4; ++cc) T[i][cc] = Tn[i][cc];
                }
            }
            float e1x = T[0][2] * 3.75f;
            float e1y = T[1][2] * 3.75f;
            float e1z = T[2][2] * 3.75f;
            float p0 = T[0][3];
            float p1 = T[1][3];
            float p2 = T[2][3] + 1.702f;
            float p3 = e1x + T[0][3];
            float p4 = e1y + T[1][3];
            float p5 = e1z + T[2][3] + 1.702f;
            const float* xp = &x_pre[be * 6];
            float dx0 = 100.0f * p0 - xp[0];
            float dx1 = 100.0f * p1 - xp[1];
            float dx2 = 100.0f * p2 - xp[2];
            float dx3 = 100.0f * p3 - xp[3];
            float dx4 = 100.0f * p4 - xp[4];
            float dx5 = 100.0f * p5 - xp[5];
            err = sqrtf(dx0 * dx0 + dx1 * dx1 + dx2 * dx2) +
                  sqrtf(dx3 * dx3 + dx4 * dx4 + dx5 * dx5);
        }
        float e0 = __shfl(err, 0, 64);
        float e1 = __shfl(err, 1, 64);
        int sel = (e1 < e0) ? 1 : 0;   // first index wins ties
        float jsel[8];
#pragma unroll
        for (int n = 0; n < 8; ++n) jsel[n] = __shfl(jq[n], sel, 64);
        if (lane == 0) {
#pragma unroll
            for (int n = 0; n < 8; ++n) out[be * NACT + n] = jsel[n];
        }
    }
}

// ===========================================================================
extern "C" void kernel_launch(void* const* d_in, const int* in_sizes, int n_in,
                              void* d_out, int out_size, void* d_ws, size_t ws_size,
                              hipStream_t stream) {
    const float* x_pre = (const float*)d_in[0];
    const float* noise = (const float*)d_in[1];
    const float* W_in  = (const float*)d_in[2];
    const float* b_in  = (const float*)d_in[3];
    const float* W1    = (const float*)d_in[4];
    const float* b1    = (const float*)d_in[5];
    const float* W2    = (const float*)d_in[6];
    const float* b2    = (const float*)d_in[7];
    const float* W3    = (const float*)d_in[8];
    const float* b3    = (const float*)d_in[9];
    const float* W4    = (const float*)d_in[10];
    const float* b4    = (const float*)d_in[11];
    const float* W_out = (const float*)d_in[12];
    const float* b_out = (const float*)d_in[13];

    // DDIM last-step coefficients (only the last loop iteration matters:
    // z is overwritten every iteration in the reference, nz never updated).
    double ab_c = exp(-0.1 * 50.0 / 1000.0 - 0.5 * (10.0 - 0.1) * 2500.0 / 1.0e6);
    float c1 = (float)sqrt(1.0 / ab_c);
    float c2 = (float)(-sqrt((1.0 - ab_c) / ab_c));
    float c3 = (float)sqrt(1.0 - ab_c);

    char* base = (char*)d_ws;
    u16* wt = (u16*)base;                        // 4 layers x (hi,lo) frag planes = 4 MB
    float* partials = (float*)(base + 4194304);  // 4x512

    k_prep<<<dim3(16, 16, 5), 256, 0, stream>>>(W1, W2, W3, W4, W_in, wt, partials);
    k_mlp<<<256, 512, 0, stream>>>(x_pre, noise, W_in, b_in, partials, wt,
                                   b1, b2, b3, b4, W_out, b_out,
                                   (float*)d_out, c1, c2, c3);
}